// Round 7
// baseline (870.373 us; speedup 1.0000x reference)
//
#include <hip/hip_runtime.h>

#define D_NODE 128
#define D_EDGE 64
#define D_IN 192
#define D_OUT 128
#define NBLK 512

// fp32 -> bf16 (RNE)
static __device__ __forceinline__ unsigned f2bf(float f) {
    unsigned u = __float_as_uint(f);
    return (u + 0x7fffu + ((u >> 16) & 1u)) >> 16;
}

// Manual grid barrier: per-instance counter (zeroed by pre-launch memset),
// leader-thread arrive + spin, device-scope fences. Same pattern ROCm's
// cooperative_groups grid sync uses; avoids hipLaunchCooperativeKernel,
// which failed silently in R6. Safe: launch_bounds(256,4) -> 4 blocks/CU
// capacity (1024); we launch 512 (2x margin), so all blocks co-resident.
static __device__ __forceinline__ void grid_barrier(int* ctr, int nblocks) {
    __syncthreads();
    if (threadIdx.x == 0) {
        __threadfence();
        __hip_atomic_fetch_add(ctr, 1, __ATOMIC_ACQ_REL, __HIP_MEMORY_SCOPE_AGENT);
        while (__hip_atomic_load(ctr, __ATOMIC_ACQUIRE, __HIP_MEMORY_SCOPE_AGENT) < nblocks) {
            __builtin_amdgcn_s_sleep(2);
        }
        __threadfence();
    }
    __syncthreads();
}

// One kernel: rank+xb-pack | scan | place | per-chunk gather+gemm.
// cnt and barrier counters are zeroed by one tiny memset before launch.
__global__ __launch_bounds__(256, 4) void k_fused(
        const int* __restrict__ ei,          // [2E]: src [0,E), dst [E,2E)
        const float2* __restrict__ x2, int nx2,
        const float* __restrict__ ef,
        const float* __restrict__ W, const float* __restrict__ b,
        int* __restrict__ cnt, int* __restrict__ ctr,
        int* __restrict__ offsets, int* __restrict__ rank,
        int2* __restrict__ csr, unsigned* __restrict__ xb,
        float* __restrict__ out, int N, int E) {
    __shared__ float sAgg[16][D_IN];
    __shared__ int scnt[16];
    __shared__ int swsum[8];

    const int tid   = threadIdx.x;
    const int lane  = tid & 63;
    const int wid   = tid >> 6;
    const int gtid  = blockIdx.x * 256 + tid;
    const int gsize = gridDim.x * 256;
    const int nblocks = gridDim.x;
    const int* dst  = ei + E;

    // ---- phase 1: per-edge rank (histogram) + x bf16 pack ----
    for (int e = gtid; e < E; e += gsize) rank[e] = atomicAdd(&cnt[dst[e]], 1);
    for (int i = gtid; i < nx2; i += gsize) {
        float2 v = x2[i];
        xb[i] = f2bf(v.x) | (f2bf(v.y) << 16);
    }
    grid_barrier(&ctr[0], nblocks);

    // ---- phase 2: exclusive scan of cnt -> offsets (block 0 only) ----
    if (blockIdx.x == 0) {
        const int CH = (N + 255) / 256;      // 40 for N=10000
        int i0 = tid * CH;
        int lsum = 0;
        for (int c = 0; c < CH; ++c) {
            int i = i0 + c;
            if (i < N) lsum += cnt[i];
        }
        int incl = lsum;
        for (int off = 1; off < 64; off <<= 1) {
            int t = __shfl_up(incl, off, 64);
            if (lane >= off) incl += t;
        }
        if (lane == 63) swsum[wid] = incl;
        __syncthreads();
        if (tid == 0) {
            int r = 0;
            for (int w = 0; w < 4; ++w) { int v = swsum[w]; swsum[w] = r; r += v; }
            swsum[4] = r;
        }
        __syncthreads();
        int run = swsum[wid] + incl - lsum;   // exclusive prefix for this thread
        for (int c = 0; c < CH; ++c) {
            int i = i0 + c;
            if (i < N) { int v = cnt[i]; offsets[i] = run; run += v; }
        }
        if (tid == 0) offsets[N] = swsum[4];
    }
    grid_barrier(&ctr[1], nblocks);

    // ---- phase 3: atomic-free placement, x4 vectorized ----
    {
        int E4 = E >> 2;
        for (int i = gtid; i < E4; i += gsize) {
            int e = i * 4;
            int4 s4 = *(const int4*)(ei + e);
            int4 d4 = *(const int4*)(dst + e);
            int4 r4 = *(const int4*)(rank + e);
            csr[offsets[d4.x] + r4.x] = make_int2(s4.x, e + 0);
            csr[offsets[d4.y] + r4.y] = make_int2(s4.y, e + 1);
            csr[offsets[d4.z] + r4.z] = make_int2(s4.z, e + 2);
            csr[offsets[d4.w] + r4.w] = make_int2(s4.w, e + 3);
        }
        for (int e = (E & ~3) + gtid; e < E; e += gsize)
            csr[offsets[dst[e]] + rank[e]] = make_int2(ei[e], e);
    }
    grid_barrier(&ctr[2], nblocks);

    // ---- phase 4: gather+gemm fused per 16-node chunk ----
    // Each block: 4 waves x 4 nodes -> sums straight into LDS sAgg (no agg
    // global round-trip), then the block GEMMs its own 16 rows.
    const int nchunks = (N + 15) / 16;
    for (int c = blockIdx.x; c < nchunks; c += nblocks) {
        __syncthreads();                      // WAR guard on sAgg
        int n0 = c * 16;
        for (int m = wid; m < 16; m += 4) {
            int node = n0 + m;
            if (node >= N) { if (lane == 0) scnt[m] = 0; continue; }
            int start = offsets[node];
            int end = offsets[node + 1];
            float ax[4] = {0.f, 0.f, 0.f, 0.f};
            float ay[4] = {0.f, 0.f, 0.f, 0.f};
            float az[4] = {0.f, 0.f, 0.f, 0.f};
            for (int base = start; base < end; base += 64) {
                int mm = end - base;
                if (mm > 64) mm = 64;
                int2 ent = make_int2(0, 0);
                if (lane < mm) {
                    long long raw = __builtin_nontemporal_load(
                        (const long long*)(csr + base + lane));
                    ent.x = (int)(raw & 0xffffffffLL);
                    ent.y = (int)(raw >> 32);
                }
                int j = 0;
                for (; j + 8 <= mm; j += 8) {
                    unsigned xv[8];
                    float    ev[8];
#pragma unroll
                    for (int u = 0; u < 8; ++u) {
                        int s  = __shfl(ent.x, j + u, 64);
                        int id = __shfl(ent.y, j + u, 64);
                        xv[u] = xb[(unsigned)s * 64u + lane];
                        ev[u] = __builtin_nontemporal_load(ef + (unsigned)id * 64u + lane);
                    }
#pragma unroll
                    for (int u = 0; u < 8; ++u) {
                        ax[u & 3] += __uint_as_float(xv[u] << 16);
                        ay[u & 3] += __uint_as_float(xv[u] & 0xffff0000u);
                        az[u & 3] += ev[u];
                    }
                }
                for (; j < mm; ++j) {
                    int s  = __shfl(ent.x, j, 64);
                    int id = __shfl(ent.y, j, 64);
                    unsigned xv = xb[(unsigned)s * 64u + lane];
                    float    ev = __builtin_nontemporal_load(ef + (unsigned)id * 64u + lane);
                    ax[0] += __uint_as_float(xv << 16);
                    ay[0] += __uint_as_float(xv & 0xffff0000u);
                    az[0] += ev;
                }
            }
            float a0 = (ax[0] + ax[1]) + (ax[2] + ax[3]);
            float a1 = (ay[0] + ay[1]) + (ay[2] + ay[3]);
            float a2 = (az[0] + az[1]) + (az[2] + az[3]);
            *(float2*)&sAgg[m][2 * lane] = make_float2(a0, a1);
            sAgg[m][128 + lane] = a2;
            if (lane == 0) scnt[m] = end - start;
        }
        __syncthreads();
        // gemm: out[n,o] = sAgg[n-n0,:]@W[:,o]/cnt + b[o]
        int o = tid & 127;
        int g = tid >> 7;
        float acc[8];
#pragma unroll
        for (int m = 0; m < 8; ++m) acc[m] = 0.0f;
        for (int k = 0; k < D_IN; k += 4) {
            float w0 = W[(k + 0) * D_OUT + o];
            float w1 = W[(k + 1) * D_OUT + o];
            float w2 = W[(k + 2) * D_OUT + o];
            float w3 = W[(k + 3) * D_OUT + o];
#pragma unroll
            for (int m = 0; m < 8; ++m) {
                const float4 av = *(const float4*)(&sAgg[g * 8 + m][k]);
                acc[m] += av.x * w0 + av.y * w1 + av.z * w2 + av.w * w3;
            }
        }
        float bo = b[o];
#pragma unroll
        for (int m = 0; m < 8; ++m) {
            int n = n0 + g * 8 + m;
            if (n < N) {
                int cdeg = scnt[g * 8 + m];
                float v = (cdeg > 0) ? (acc[m] / (float)cdeg + bo) : 0.0f;
                __builtin_nontemporal_store(v, &out[(size_t)n * D_OUT + o]);
            }
        }
    }
}

extern "C" void kernel_launch(void* const* d_in, const int* in_sizes, int n_in,
                              void* d_out, int out_size, void* d_ws, size_t ws_size,
                              hipStream_t stream) {
    const float* x  = (const float*)d_in[0];
    const int*   ei = (const int*)d_in[1];   // [2, E] flat
    const float* ef = (const float*)d_in[2];
    const float* W  = (const float*)d_in[3];
    const float* b  = (const float*)d_in[4];
    float* out = (float*)d_out;

    const int N = in_sizes[0] / D_NODE;
    const int E = in_sizes[2] / D_EDGE;
    const int nx2 = in_sizes[0] / 2;

    auto align64 = [](size_t v) { return (v + 63) & ~(size_t)63; };
    char* ws = (char*)d_ws;
    size_t o_cnt = 0;
    size_t o_ctr = align64(o_cnt + (size_t)N * 4);        // 4 barrier counters
    size_t o_off = align64(o_ctr + 64);
    size_t o_rnk = align64(o_off + (size_t)(N + 1) * 4);
    size_t o_csr = align64(o_rnk + (size_t)E * 4);
    size_t o_xb  = align64(o_csr + (size_t)E * 8);
    int*  cnt     = (int*)(ws + o_cnt);
    int*  ctr     = (int*)(ws + o_ctr);
    int*  offsets = (int*)(ws + o_off);
    int*  rank    = (int*)(ws + o_rnk);
    int2* csr     = (int2*)(ws + o_csr);
    unsigned* xb  = (unsigned*)(ws + o_xb);

    // zero cnt + barrier counters in one tiny memset
    hipMemsetAsync(ws, 0, o_ctr + 64, stream);
    k_fused<<<NBLK, 256, 0, stream>>>(ei, (const float2*)x, nx2, ef, W, b,
                                      cnt, ctr, offsets, rank, csr, xb,
                                      out, N, E);
}

// Round 8
// 321.950 us; speedup vs baseline: 2.7034x; 2.7034x over previous
//
#include <hip/hip_runtime.h>

#define D_NODE 128
#define D_EDGE 64
#define D_IN 192
#define D_OUT 128

// fp32 -> bf16 (RNE)
static __device__ __forceinline__ unsigned f2bf(float f) {
    unsigned u = __float_as_uint(f);
    return (u + 0x7fffu + ((u >> 16) & 1u)) >> 16;
}

// ---------------- CSR build (R5-proven) ----------------

// Histogram rank + x bf16 pack in one pass.
__global__ void k_rank(const int* __restrict__ dst, int* __restrict__ cnt,
                       int* __restrict__ rank, const float2* __restrict__ x2,
                       unsigned* __restrict__ xb, int nx2, int E) {
    int e = blockIdx.x * 256 + threadIdx.x;
    if (e < E) rank[e] = atomicAdd(&cnt[dst[e]], 1);
    if (e < nx2) {
        float2 v = x2[e];
        xb[e] = f2bf(v.x) | (f2bf(v.y) << 16);
    }
}

// Single-block scan (N <= 16384).
__global__ __launch_bounds__(1024) void k_scan(const int* __restrict__ cnt,
                                               int* __restrict__ offsets, int N) {
    __shared__ int wsum[16];
    int tid = threadIdx.x;
    int lane = tid & 63, wid = tid >> 6;
    const int CH = (N + 1023) / 1024;
    int i0 = tid * CH;
    int local[16];
    int lsum = 0;
    for (int c = 0; c < CH; ++c) {
        int i = i0 + c;
        int v = (i < N) ? cnt[i] : 0;
        local[c] = v;
        lsum += v;
    }
    int incl = lsum;
    for (int off = 1; off < 64; off <<= 1) {
        int t = __shfl_up(incl, off, 64);
        if (lane >= off) incl += t;
    }
    if (lane == 63) wsum[wid] = incl;
    __syncthreads();
    if (wid == 0) {
        int s = (lane < 16) ? wsum[lane] : 0;
        for (int off = 1; off < 16; off <<= 1) {
            int t = __shfl_up(s, off, 64);
            if (lane >= off) s += t;
        }
        if (lane < 16) wsum[lane] = s;
    }
    __syncthreads();
    int waveoff = (wid > 0) ? wsum[wid - 1] : 0;
    int run = waveoff + incl - lsum;
    for (int c = 0; c < CH; ++c) {
        int i = i0 + c;
        if (i < N) { offsets[i] = run; run += local[c]; }
    }
    if (tid == 0) offsets[N] = wsum[15];
}

// Atomic-free placement, x4 vectorized.
__global__ void k_place(const int* __restrict__ ei, const int* __restrict__ offsets,
                        const int* __restrict__ rank, int2* __restrict__ csr, int E) {
    int i = blockIdx.x * 256 + threadIdx.x;
    int e = i * 4;
    if (e + 4 <= E) {
        int4 s4 = *(const int4*)(ei + e);
        int4 d4 = *(const int4*)(ei + E + e);
        int4 r4 = *(const int4*)(rank + e);
        csr[offsets[d4.x] + r4.x] = make_int2(s4.x, e + 0);
        csr[offsets[d4.y] + r4.y] = make_int2(s4.y, e + 1);
        csr[offsets[d4.z] + r4.z] = make_int2(s4.z, e + 2);
        csr[offsets[d4.w] + r4.w] = make_int2(s4.w, e + 3);
    } else {
        for (; e < E; ++e)
            csr[offsets[ei[E + e]] + rank[e]] = make_int2(ei[e], e);
    }
}

// ---------------- fused gather + gemm ----------------
// One block per 16-node chunk, 512 threads (8 waves). Each wave gathers 2
// nodes' sums (bf16 x via L2-resident xb; nt ef stream) directly into LDS,
// then the block GEMMs its 16 rows: out[n,o] = sAgg[n,:]@W[:,o]/cnt + b[o].
// Kills the agg global round-trip (~30 MB) and one dispatch vs R5.
// 625 blocks x 8 waves ~= 19 waves/CU resident — gather MLP preserved.
__global__ void k_gg(
        const unsigned* __restrict__ xb, const float* __restrict__ ef,
        const int* __restrict__ offsets, const int2* __restrict__ csr,
        const float* __restrict__ W, const float* __restrict__ b,
        float* __restrict__ out, int N) {
    __shared__ float sAgg[16][D_IN];
    __shared__ int scnt[16];
    const int tid  = threadIdx.x;
    const int lane = tid & 63;
    const int wid  = tid >> 6;           // 0..7
    const int n0   = blockIdx.x * 16;

    // ---- gather: 2 nodes per wave ----
    for (int m = wid; m < 16; m += 8) {
        int node = n0 + m;
        float ax[4] = {0.f, 0.f, 0.f, 0.f};
        float ay[4] = {0.f, 0.f, 0.f, 0.f};
        float az[4] = {0.f, 0.f, 0.f, 0.f};
        int start = 0, end = 0;
        if (node < N) {
            start = offsets[node];
            end = offsets[node + 1];
            for (int base = start; base < end; base += 64) {
                int mm = end - base;
                if (mm > 64) mm = 64;
                int2 ent = make_int2(0, 0);
                if (lane < mm) {
                    long long raw = __builtin_nontemporal_load(
                        (const long long*)(csr + base + lane));
                    ent.x = (int)(raw & 0xffffffffLL);
                    ent.y = (int)(raw >> 32);
                }
                int j = 0;
                for (; j + 8 <= mm; j += 8) {
                    unsigned xv[8];
                    float    ev[8];
#pragma unroll
                    for (int u = 0; u < 8; ++u) {
                        int s  = __shfl(ent.x, j + u, 64);
                        int id = __shfl(ent.y, j + u, 64);
                        xv[u] = xb[(unsigned)s * 64u + lane];
                        ev[u] = __builtin_nontemporal_load(ef + (unsigned)id * 64u + lane);
                    }
#pragma unroll
                    for (int u = 0; u < 8; ++u) {
                        ax[u & 3] += __uint_as_float(xv[u] << 16);
                        ay[u & 3] += __uint_as_float(xv[u] & 0xffff0000u);
                        az[u & 3] += ev[u];
                    }
                }
                for (; j < mm; ++j) {
                    int s  = __shfl(ent.x, j, 64);
                    int id = __shfl(ent.y, j, 64);
                    unsigned xv = xb[(unsigned)s * 64u + lane];
                    float    ev = __builtin_nontemporal_load(ef + (unsigned)id * 64u + lane);
                    ax[0] += __uint_as_float(xv << 16);
                    ay[0] += __uint_as_float(xv & 0xffff0000u);
                    az[0] += ev;
                }
            }
        }
        float a0 = (ax[0] + ax[1]) + (ax[2] + ax[3]);
        float a1 = (ay[0] + ay[1]) + (ay[2] + ay[3]);
        float a2 = (az[0] + az[1]) + (az[2] + az[3]);
        *(float2*)&sAgg[m][2 * lane] = make_float2(a0, a1);   // 2-way bank alias: free
        sAgg[m][128 + lane] = a2;
        if (lane == 0) scnt[m] = end - start;
    }
    __syncthreads();

    // ---- gemm: 512 threads; o = tid&127, g = tid>>7 handles nodes g*4..g*4+3 ----
    int o = tid & 127;
    int g = tid >> 7;                    // 0..3
    float acc[4];
#pragma unroll
    for (int m = 0; m < 4; ++m) acc[m] = 0.0f;
    for (int k = 0; k < D_IN; k += 4) {
        float w0 = W[(k + 0) * D_OUT + o];
        float w1 = W[(k + 1) * D_OUT + o];
        float w2 = W[(k + 2) * D_OUT + o];
        float w3 = W[(k + 3) * D_OUT + o];
#pragma unroll
        for (int m = 0; m < 4; ++m) {
            const float4 av = *(const float4*)(&sAgg[g * 4 + m][k]);
            acc[m] += av.x * w0 + av.y * w1 + av.z * w2 + av.w * w3;
        }
    }
    float bo = b[o];
#pragma unroll
    for (int m = 0; m < 4; ++m) {
        int n = n0 + g * 4 + m;
        if (n < N) {
            int c = scnt[g * 4 + m];
            float v = (c > 0) ? (acc[m] / (float)c + bo) : 0.0f;
            __builtin_nontemporal_store(v, &out[(size_t)n * D_OUT + o]);
        }
    }
}

extern "C" void kernel_launch(void* const* d_in, const int* in_sizes, int n_in,
                              void* d_out, int out_size, void* d_ws, size_t ws_size,
                              hipStream_t stream) {
    const float* x  = (const float*)d_in[0];
    const int*   ei = (const int*)d_in[1];   // [2, E] flat: src [0,E), dst [E,2E)
    const float* ef = (const float*)d_in[2];
    const float* W  = (const float*)d_in[3];
    const float* b  = (const float*)d_in[4];
    float* out = (float*)d_out;

    const int N = in_sizes[0] / D_NODE;
    const int E = in_sizes[2] / D_EDGE;
    const int nx2 = in_sizes[0] / 2;

    auto align64 = [](size_t v) { return (v + 63) & ~(size_t)63; };
    char* ws = (char*)d_ws;
    size_t o_cnt = 0;
    size_t o_off = align64(o_cnt + (size_t)N * 4);
    size_t o_rnk = align64(o_off + (size_t)(N + 1) * 4);
    size_t o_csr = align64(o_rnk + (size_t)E * 4);
    size_t o_xb  = align64(o_csr + (size_t)E * 8);
    int*  cnt     = (int*)(ws + o_cnt);
    int*  offsets = (int*)(ws + o_off);
    int*  rank    = (int*)(ws + o_rnk);
    int2* csr     = (int2*)(ws + o_csr);
    unsigned* xb  = (unsigned*)(ws + o_xb);

    int gridR = ((E > nx2 ? E : nx2) + 255) / 256;
    hipMemsetAsync(cnt, 0, (size_t)N * 4, stream);
    k_rank<<<gridR, 256, 0, stream>>>(ei + E, cnt, rank, (const float2*)x, xb, nx2, E);
    k_scan<<<1, 1024, 0, stream>>>(cnt, offsets, N);
    k_place<<<(E / 4 + 255) / 256, 256, 0, stream>>>(ei, offsets, rank, csr, E);
    k_gg<<<(N + 15) / 16, 512, 0, stream>>>(xb, ef, offsets, csr, W, b, out, N);
}